// Round 1
// baseline (863.656 us; speedup 1.0000x reference)
//
#include <hip/hip_runtime.h>
#include <hip/hip_bf16.h>

typedef unsigned short u16;
typedef __attribute__((ext_vector_type(8))) __bf16 bf16x8;   // 4 VGPRs: MFMA A/B frag
typedef __attribute__((ext_vector_type(4))) float f32x4;     // MFMA C/D frag
typedef __attribute__((ext_vector_type(4))) float f4v;
typedef __attribute__((ext_vector_type(8))) unsigned short u16x8;

__device__ __forceinline__ u16 f32_to_bf16(float f) {
  unsigned int u = __builtin_bit_cast(unsigned int, f);
  u += 0x7FFFu + ((u >> 16) & 1u);   // RNE (inputs are finite, no NaN handling needed)
  return (u16)(u >> 16);
}

// async 16B global -> LDS (global_load_lds_dwordx4). LDS dest: wave-uniform base + lane*16.
__device__ __forceinline__ void async_ld16(const void* gsrc, void* ldst) {
  __builtin_amdgcn_global_load_lds(
      (__attribute__((address_space(1))) void*)(unsigned long long)gsrc,
      (__attribute__((address_space(3))) void*)(unsigned long long)ldst,
      16, 0, 0);
}

// ---------------- fp32 -> bf16 elementwise (x) ----------------
__global__ void cvt_kernel(const float* __restrict__ in, u16* __restrict__ out, int n8) {
  int i = blockIdx.x * blockDim.x + threadIdx.x;
  if (i >= n8) return;
  const f4v* p = (const f4v*)(in + (size_t)i * 8);
  f4v a = p[0], b = p[1];
  u16x8 r;
  r[0] = f32_to_bf16(a[0]); r[1] = f32_to_bf16(a[1]);
  r[2] = f32_to_bf16(a[2]); r[3] = f32_to_bf16(a[3]);
  r[4] = f32_to_bf16(b[0]); r[5] = f32_to_bf16(b[1]);
  r[6] = f32_to_bf16(b[2]); r[7] = f32_to_bf16(b[3]);
  *(u16x8*)(out + (size_t)i * 8) = r;
}

// ------------- fp32 [E][R][C] -> bf16 [E][C][R] (weight transpose) -------------
__global__ void tpose_cvt_kernel(const float* __restrict__ in, u16* __restrict__ out,
                                 int R, int C) {
  __shared__ u16 tile[32][33];  // +1 pad breaks bank-conflict stride
  const int e = blockIdx.z;
  const int c0 = blockIdx.x * 32, r0 = blockIdx.y * 32;
  const float* src = in + (size_t)e * R * C;
  u16* dst = out + (size_t)e * R * C;
  const int tx = threadIdx.x, ty = threadIdx.y;  // block (32,8)
#pragma unroll
  for (int i = 0; i < 32; i += 8)
    tile[ty + i][tx] = f32_to_bf16(src[(size_t)(r0 + ty + i) * C + (c0 + tx)]);
  __syncthreads();
#pragma unroll
  for (int i = 0; i < 32; i += 8)
    dst[(size_t)(c0 + ty + i) * R + (r0 + tx)] = tile[tx][ty + i];
}

// ---------------- grouped GEMM: out[m][n] = A[m][:] . Bt[e][n][:] ----------------
// A: bf16 [Mtot][K] row-major (k-contiguous). Bt: bf16 [E][Nn][K] (transposed, k-contiguous).
// 128x128 tile, BK=32, 4 waves each 64x64 via 4x4 grid of 16x16x32 MFMA.
// FUSE=1: out = bf16 gelu(acc) (intermediate); FUSE=0: out = f32 acc (final).
template <int FUSE>
__global__ __launch_bounds__(256)
void grouped_gemm(const u16* __restrict__ A, const u16* __restrict__ Bt,
                  void* __restrict__ Out, const int* __restrict__ tokens,
                  int Mtot, int K, int Nn) {
  // resolve (expert, m-tile) from ragged group sizes; grid.y = Mtot/128 + E slots
  const int slot = blockIdx.y;
  int row_start = 0, tiles_before = 0;
  int expert = -1, my_row0 = 0, rows_valid = 0;
#pragma unroll
  for (int e = 0; e < 8; ++e) {
    int t = tokens[e];
    int nt = (t + 127) >> 7;
    if (expert < 0 && slot >= tiles_before && slot < tiles_before + nt) {
      expert = e;
      int mi = slot - tiles_before;
      my_row0 = row_start + mi * 128;
      rows_valid = t - mi * 128;
      if (rows_valid > 128) rows_valid = 128;
    }
    tiles_before += nt;
    row_start += t;
  }
  if (expert < 0) return;  // idle slack slot

  const int n0 = blockIdx.x * 128;
  const u16* Bq = Bt + (size_t)expert * Nn * K + (size_t)n0 * K;

  __shared__ __align__(16) u16 lA[128 * 32];  // 8 KB, row-major [m][k]
  __shared__ __align__(16) u16 lB[128 * 32];  // 8 KB, row-major [n][k]

  const int tid = threadIdx.x;
  const int lane = tid & 63;
  const int wave = tid >> 6;
  const int wm = (wave >> 1) * 64;  // wave's 64-row slab
  const int wn = (wave & 1) * 64;   // wave's 64-col slab
  const int fr = lane & 15;         // frag row/col within 16
  const int fq = lane >> 4;         // quad (k-group / acc row group)

  f32x4 acc[4][4];
#pragma unroll
  for (int i = 0; i < 4; ++i)
#pragma unroll
    for (int j = 0; j < 4; ++j) acc[i][j] = (f32x4){0.f, 0.f, 0.f, 0.f};

  // staging geometry: 512 slots of 16B per tile; slot s -> row s>>2, k-group s&3.
  const int sr = tid >> 2;        // 0..63
  const int sc = (tid & 3) * 8;   // 0,8,16,24 (bf16 elems)

  for (int k0 = 0; k0 < K; k0 += 32) {
#pragma unroll
    for (int h = 0; h < 2; ++h) {
      int r = h * 64 + sr;
      int ga = my_row0 + r;
      if (ga > Mtot - 1) ga = Mtot - 1;  // clamp: garbage rows are store-masked later
      async_ld16(A + (size_t)ga * K + (size_t)(k0 + sc), &lA[(size_t)r * 32 + sc]);
      async_ld16(Bq + (size_t)r * K + (size_t)(k0 + sc), &lB[(size_t)r * 32 + sc]);
    }
    __syncthreads();  // drains vmcnt: LDS tiles ready

    bf16x8 aF[4], bF[4];
#pragma unroll
    for (int i = 0; i < 4; ++i)
      aF[i] = *(const bf16x8*)&lA[(wm + i * 16 + fr) * 32 + fq * 8];
#pragma unroll
    for (int j = 0; j < 4; ++j)
      bF[j] = *(const bf16x8*)&lB[(wn + j * 16 + fr) * 32 + fq * 8];
#pragma unroll
    for (int i = 0; i < 4; ++i)
#pragma unroll
      for (int j = 0; j < 4; ++j)
        acc[i][j] = __builtin_amdgcn_mfma_f32_16x16x32_bf16(aF[i], bF[j], acc[i][j], 0, 0, 0);
    __syncthreads();  // all reads done before next iter's async stores land
  }

  // epilogue. C/D layout: col = lane&15, row = (lane>>4)*4 + reg  [m89-verified]
  if (FUSE) {
    u16* Op = (u16*)Out;
#pragma unroll
    for (int i = 0; i < 4; ++i) {
#pragma unroll
      for (int r = 0; r < 4; ++r) {
        int lrow = wm + i * 16 + fq * 4 + r;
        if (lrow < rows_valid) {
          size_t base = (size_t)(my_row0 + lrow) * Nn + (size_t)(n0 + wn + fr);
#pragma unroll
          for (int j = 0; j < 4; ++j) {
            float v = acc[i][j][r];
            float g = 0.5f * v * (1.0f + erff(v * 0.70710678118654752f));  // exact gelu
            Op[base + j * 16] = f32_to_bf16(g);
          }
        }
      }
    }
  } else {
    float* Op = (float*)Out;
#pragma unroll
    for (int i = 0; i < 4; ++i) {
#pragma unroll
      for (int r = 0; r < 4; ++r) {
        int lrow = wm + i * 16 + fq * 4 + r;
        if (lrow < rows_valid) {
          size_t base = (size_t)(my_row0 + lrow) * Nn + (size_t)(n0 + wn + fr);
#pragma unroll
          for (int j = 0; j < 4; ++j) Op[base + j * 16] = acc[i][j][r];
        }
      }
    }
  }
}

extern "C" void kernel_launch(void* const* d_in, const int* in_sizes, int n_in,
                              void* d_out, int out_size, void* d_ws, size_t ws_size,
                              hipStream_t stream) {
  (void)in_sizes; (void)n_in; (void)out_size; (void)ws_size;
  const float* x  = (const float*)d_in[0];   // [N][H]
  const float* w1 = (const float*)d_in[1];   // [E][H][F]
  const float* w2 = (const float*)d_in[2];   // [E][F][H]
  const int* tokens = (const int*)d_in[3];   // [E]

  const int N = 16384, H = 1024, F = 4096, E = 8;

  // ws layout (bf16): x 32MB | w1^T 64MB | w2^T 64MB | intermediate 128MB  (~302 MB)
  u16* x_bf  = (u16*)d_ws;
  u16* w1t   = x_bf + (size_t)N * H;       // [E][F][H]
  u16* w2t   = w1t + (size_t)E * F * H;    // [E][H][F]
  u16* inter = w2t + (size_t)E * H * F;    // [N][F]

  cvt_kernel<<<dim3((N * H / 8 + 255) / 256), dim3(256), 0, stream>>>(x, x_bf, N * H / 8);
  tpose_cvt_kernel<<<dim3(F / 32, H / 32, E), dim3(32, 8), 0, stream>>>(w1, w1t, H, F);
  tpose_cvt_kernel<<<dim3(H / 32, F / 32, E), dim3(32, 8), 0, stream>>>(w2, w2t, F, H);

  // GEMM1: [N][H] x [H][F] -> gelu -> bf16 inter [N][F]
  grouped_gemm<1><<<dim3(F / 128, N / 128 + E), dim3(256), 0, stream>>>(
      x_bf, w1t, inter, tokens, N, H, F);
  // GEMM2: [N][F] x [F][H] -> f32 out [N][H]
  grouped_gemm<0><<<dim3(H / 128, N / 128 + E), dim3(256), 0, stream>>>(
      inter, w2t, (float*)d_out, tokens, N, F, H);
}

// Round 2
// 770.594 us; speedup vs baseline: 1.1208x; 1.1208x over previous
//
#include <hip/hip_runtime.h>
#include <hip/hip_bf16.h>

typedef unsigned short u16;
typedef __attribute__((ext_vector_type(8))) __bf16 bf16x8;   // 4 VGPRs: MFMA A/B frag
typedef __attribute__((ext_vector_type(4))) float f32x4;     // MFMA C/D frag
typedef __attribute__((ext_vector_type(4))) float f4v;
typedef __attribute__((ext_vector_type(8))) unsigned short u16x8;

__device__ __forceinline__ u16 f32_to_bf16(float f) {
  unsigned int u = __builtin_bit_cast(unsigned int, f);
  u += 0x7FFFu + ((u >> 16) & 1u);   // RNE (inputs finite)
  return (u16)(u >> 16);
}

// async 16B global -> LDS (global_load_lds_dwordx4). LDS dest: wave-uniform base + lane*16.
__device__ __forceinline__ void async_ld16(const void* gsrc, void* ldst) {
  __builtin_amdgcn_global_load_lds(
      (__attribute__((address_space(1))) void*)(unsigned long long)gsrc,
      (__attribute__((address_space(3))) void*)(unsigned long long)ldst,
      16, 0, 0);
}

// ---------------- fp32 -> bf16 elementwise (x) ----------------
__global__ void cvt_kernel(const float* __restrict__ in, u16* __restrict__ out, int n8) {
  int i = blockIdx.x * blockDim.x + threadIdx.x;
  if (i >= n8) return;
  const f4v* p = (const f4v*)(in + (size_t)i * 8);
  f4v a = p[0], b = p[1];
  u16x8 r;
  r[0] = f32_to_bf16(a[0]); r[1] = f32_to_bf16(a[1]);
  r[2] = f32_to_bf16(a[2]); r[3] = f32_to_bf16(a[3]);
  r[4] = f32_to_bf16(b[0]); r[5] = f32_to_bf16(b[1]);
  r[6] = f32_to_bf16(b[2]); r[7] = f32_to_bf16(b[3]);
  *(u16x8*)(out + (size_t)i * 8) = r;
}

// ------------- fp32 [E][R][C] -> bf16 [E][C][R] (weight transpose) -------------
__global__ void tpose_cvt_kernel(const float* __restrict__ in, u16* __restrict__ out,
                                 int R, int C) {
  __shared__ u16 tile[32][33];  // +1 pad breaks bank-conflict stride
  const int e = blockIdx.z;
  const int c0 = blockIdx.x * 32, r0 = blockIdx.y * 32;
  const float* src = in + (size_t)e * R * C;
  u16* dst = out + (size_t)e * R * C;
  const int tx = threadIdx.x, ty = threadIdx.y;  // block (32,8)
#pragma unroll
  for (int i = 0; i < 32; i += 8)
    tile[ty + i][tx] = f32_to_bf16(src[(size_t)(r0 + ty + i) * C + (c0 + tx)]);
  __syncthreads();
#pragma unroll
  for (int i = 0; i < 32; i += 8)
    dst[(size_t)(c0 + ty + i) * R + (r0 + tx)] = tile[tx][ty + i];
}

// ---------------- grouped GEMM: out[m][n] = A[m][:] . Bt[e][n][:] ----------------
// A: bf16 [Mtot][K] row-major (k-contiguous). Bt: bf16 [E][Nn][K].
// 128x128 tile, BK=32, double-buffered LDS (one barrier/iter), XOR-swizzled chunks.
// LDS slot (row r, chunk c) holds global k-chunk g = c ^ ((r>>1)&3)  -> 2-way banks.
// FUSE=1: out = bf16 gelu(acc); FUSE=0: out = f32 acc.
template <int FUSE>
__global__ __launch_bounds__(256)
void grouped_gemm(const u16* __restrict__ A, const u16* __restrict__ Bt,
                  void* __restrict__ Out, const int* __restrict__ tokens,
                  int Mtot, int K, int Nn) {
  // resolve (expert, m-tile) from ragged group sizes; grid.y = Mtot/128 + E slots
  const int slot = blockIdx.y;
  int row_start = 0, tiles_before = 0;
  int expert = -1, my_row0 = 0, rows_valid = 0;
#pragma unroll
  for (int e = 0; e < 8; ++e) {
    int t = tokens[e];
    int nt = (t + 127) >> 7;
    if (expert < 0 && slot >= tiles_before && slot < tiles_before + nt) {
      expert = e;
      int mi = slot - tiles_before;
      my_row0 = row_start + mi * 128;
      rows_valid = t - mi * 128;
      if (rows_valid > 128) rows_valid = 128;
    }
    tiles_before += nt;
    row_start += t;
  }
  if (expert < 0) return;  // idle slack slot

  const int n0 = blockIdx.x * 128;
  const u16* Bq = Bt + (size_t)expert * Nn * K + (size_t)n0 * K;

  __shared__ __align__(16) u16 lA[2][128 * 32];  // 2 x 8 KB
  __shared__ __align__(16) u16 lB[2][128 * 32];

  const int tid = threadIdx.x;
  const int lane = tid & 63;
  const int wave = tid >> 6;
  const int wm = (wave >> 1) * 64;
  const int wn = (wave & 1) * 64;
  const int fr = lane & 15;
  const int fq = lane >> 4;

  f32x4 acc[4][4];
#pragma unroll
  for (int i = 0; i < 4; ++i)
#pragma unroll
    for (int j = 0; j < 4; ++j) acc[i][j] = (f32x4){0.f, 0.f, 0.f, 0.f};

  // staging: thread tid fills LDS slot (r = h*64 + (tid>>2), c = tid&3), h=0,1,
  // at elem offset h*2048 + tid*8. Source chunk g = c ^ ((r>>1)&3).
  const int sr = tid >> 2;
  const int swz = ((tid & 3) ^ ((sr >> 1) & 3)) * 8;  // source elem offset within 32-k strip
  int ga0 = my_row0 + sr;       if (ga0 > Mtot - 1) ga0 = Mtot - 1;  // clamp; store-masked
  int ga1 = my_row0 + 64 + sr;  if (ga1 > Mtot - 1) ga1 = Mtot - 1;
  const u16* pA0 = A + (size_t)ga0 * K + swz;
  const u16* pA1 = A + (size_t)ga1 * K + swz;
  const u16* pB0 = Bq + (size_t)sr * K + swz;
  const u16* pB1 = Bq + (size_t)(64 + sr) * K + swz;

  // fragment read: chunk fq of row lives at swizzled column (fq ^ ((fr>>1)&3))
  const int cswz = (fq ^ ((fr >> 1) & 3)) * 8;

  // prefetch tile 0 into buffer 0
  async_ld16(pA0, &lA[0][tid * 8]);
  async_ld16(pA1, &lA[0][2048 + tid * 8]);
  async_ld16(pB0, &lB[0][tid * 8]);
  async_ld16(pB1, &lB[0][2048 + tid * 8]);

  int buf = 0;
  for (int k0 = 0; k0 < K; k0 += 32) {
    __syncthreads();  // vmcnt(0): tile `buf` published; lgkmcnt(0): buf^1 reads done
    if (k0 + 32 < K) {
      const int nb = buf ^ 1;
      async_ld16(pA0 + k0 + 32, &lA[nb][tid * 8]);
      async_ld16(pA1 + k0 + 32, &lA[nb][2048 + tid * 8]);
      async_ld16(pB0 + k0 + 32, &lB[nb][tid * 8]);
      async_ld16(pB1 + k0 + 32, &lB[nb][2048 + tid * 8]);
    }

    bf16x8 aF[4], bF[4];
#pragma unroll
    for (int i = 0; i < 4; ++i)
      aF[i] = *(const bf16x8*)&lA[buf][(wm + i * 16 + fr) * 32 + cswz];
#pragma unroll
    for (int j = 0; j < 4; ++j)
      bF[j] = *(const bf16x8*)&lB[buf][(wn + j * 16 + fr) * 32 + cswz];
#pragma unroll
    for (int i = 0; i < 4; ++i)
#pragma unroll
      for (int j = 0; j < 4; ++j)
        acc[i][j] = __builtin_amdgcn_mfma_f32_16x16x32_bf16(aF[i], bF[j], acc[i][j], 0, 0, 0);
    buf ^= 1;
  }

  // epilogue. C/D layout: col = lane&15, row = (lane>>4)*4 + reg  [m89-verified]
  if (FUSE) {
    u16* Op = (u16*)Out;
#pragma unroll
    for (int i = 0; i < 4; ++i) {
#pragma unroll
      for (int r = 0; r < 4; ++r) {
        int lrow = wm + i * 16 + fq * 4 + r;
        if (lrow < rows_valid) {
          size_t base = (size_t)(my_row0 + lrow) * Nn + (size_t)(n0 + wn + fr);
#pragma unroll
          for (int j = 0; j < 4; ++j) {
            float v = acc[i][j][r];
            float g = 0.5f * v * (1.0f + erff(v * 0.70710678118654752f));  // exact gelu
            Op[base + j * 16] = f32_to_bf16(g);
          }
        }
      }
    }
  } else {
    float* Op = (float*)Out;
#pragma unroll
    for (int i = 0; i < 4; ++i) {
#pragma unroll
      for (int r = 0; r < 4; ++r) {
        int lrow = wm + i * 16 + fq * 4 + r;
        if (lrow < rows_valid) {
          size_t base = (size_t)(my_row0 + lrow) * Nn + (size_t)(n0 + wn + fr);
#pragma unroll
          for (int j = 0; j < 4; ++j) Op[base + j * 16] = acc[i][j][r];
        }
      }
    }
  }
}

extern "C" void kernel_launch(void* const* d_in, const int* in_sizes, int n_in,
                              void* d_out, int out_size, void* d_ws, size_t ws_size,
                              hipStream_t stream) {
  (void)in_sizes; (void)n_in; (void)out_size; (void)ws_size;
  const float* x  = (const float*)d_in[0];   // [N][H]
  const float* w1 = (const float*)d_in[1];   // [E][H][F]
  const float* w2 = (const float*)d_in[2];   // [E][F][H]
  const int* tokens = (const int*)d_in[3];   // [E]

  const int N = 16384, H = 1024, F = 4096, E = 8;

  // ws layout (bf16): x 32MB | w1^T 64MB | w2^T 64MB | intermediate 128MB  (~302 MB)
  u16* x_bf  = (u16*)d_ws;
  u16* w1t   = x_bf + (size_t)N * H;       // [E][F][H]
  u16* w2t   = w1t + (size_t)E * F * H;    // [E][H][F]
  u16* inter = w2t + (size_t)E * H * F;    // [N][F]

  cvt_kernel<<<dim3((N * H / 8 + 255) / 256), dim3(256), 0, stream>>>(x, x_bf, N * H / 8);
  tpose_cvt_kernel<<<dim3(F / 32, H / 32, E), dim3(32, 8), 0, stream>>>(w1, w1t, H, F);
  tpose_cvt_kernel<<<dim3(H / 32, F / 32, E), dim3(32, 8), 0, stream>>>(w2, w2t, F, H);

  // GEMM1: [N][H] x [H][F] -> gelu -> bf16 inter [N][F]
  grouped_gemm<1><<<dim3(F / 128, N / 128 + E), dim3(256), 0, stream>>>(
      x_bf, w1t, inter, tokens, N, H, F);
  // GEMM2: [N][F] x [F][H] -> f32 out [N][H]
  grouped_gemm<0><<<dim3(H / 128, N / 128 + E), dim3(256), 0, stream>>>(
      inter, w2t, (float*)d_out, tokens, N, F, H);
}

// Round 3
// 722.701 us; speedup vs baseline: 1.1950x; 1.0663x over previous
//
#include <hip/hip_runtime.h>
#include <hip/hip_bf16.h>

typedef unsigned short u16;
typedef __attribute__((ext_vector_type(8))) __bf16 bf16x8;   // 4 VGPRs: MFMA A/B frag
typedef __attribute__((ext_vector_type(4))) float f32x4;     // MFMA C/D frag
typedef __attribute__((ext_vector_type(4))) float f4v;
typedef __attribute__((ext_vector_type(8))) unsigned short u16x8;

__device__ __forceinline__ u16 f32_to_bf16(float f) {
  unsigned int u = __builtin_bit_cast(unsigned int, f);
  u += 0x7FFFu + ((u >> 16) & 1u);   // RNE (inputs finite)
  return (u16)(u >> 16);
}

// fast gelu: v * sigmoid(1.59577*(v + 0.044715 v^3))  [tanh-form, max abs err ~3e-3]
// large +v -> exp(-t)->0 -> g=v; large -v -> exp(-t)->inf -> rcp->0 -> g=0. NaN-free.
__device__ __forceinline__ float fast_gelu(float v) {
  float v2 = v * v;
  float t = v * fmaf(0.0713548162726f, v2, 1.5957691216057308f);
  float e = __expf(-t);
  float s = __builtin_amdgcn_rcpf(1.0f + e);
  return v * s;
}

// async 16B global -> LDS (global_load_lds_dwordx4). LDS dest: wave-uniform base + lane*16.
__device__ __forceinline__ void async_ld16(const void* gsrc, void* ldst) {
  __builtin_amdgcn_global_load_lds(
      (__attribute__((address_space(1))) void*)(unsigned long long)gsrc,
      (__attribute__((address_space(3))) void*)(unsigned long long)ldst,
      16, 0, 0);
}

// ---------------- fp32 -> bf16 elementwise (x) ----------------
__global__ void cvt_kernel(const float* __restrict__ in, u16* __restrict__ out, int n8) {
  int i = blockIdx.x * blockDim.x + threadIdx.x;
  if (i >= n8) return;
  const f4v* p = (const f4v*)(in + (size_t)i * 8);
  f4v a = p[0], b = p[1];
  u16x8 r;
  r[0] = f32_to_bf16(a[0]); r[1] = f32_to_bf16(a[1]);
  r[2] = f32_to_bf16(a[2]); r[3] = f32_to_bf16(a[3]);
  r[4] = f32_to_bf16(b[0]); r[5] = f32_to_bf16(b[1]);
  r[6] = f32_to_bf16(b[2]); r[7] = f32_to_bf16(b[3]);
  *(u16x8*)(out + (size_t)i * 8) = r;
}

// ------------- fp32 [E][R][C] -> bf16 [E][C][R] (weight transpose) -------------
__global__ void tpose_cvt_kernel(const float* __restrict__ in, u16* __restrict__ out,
                                 int R, int C) {
  __shared__ u16 tile[32][33];  // +1 pad breaks bank-conflict stride
  const int e = blockIdx.z;
  const int c0 = blockIdx.x * 32, r0 = blockIdx.y * 32;
  const float* src = in + (size_t)e * R * C;
  u16* dst = out + (size_t)e * R * C;
  const int tx = threadIdx.x, ty = threadIdx.y;  // block (32,8)
#pragma unroll
  for (int i = 0; i < 32; i += 8)
    tile[ty + i][tx] = f32_to_bf16(src[(size_t)(r0 + ty + i) * C + (c0 + tx)]);
  __syncthreads();
#pragma unroll
  for (int i = 0; i < 32; i += 8)
    dst[(size_t)(c0 + ty + i) * R + (r0 + tx)] = tile[tx][ty + i];
}

// ---------------- grouped GEMM: out[m][n] = A[m][:] . Bt[e][n][:] ----------------
// A: bf16 [Mtot][K] row-major. Bt: bf16 [E][Nn][K]. 128x128 tile, BK=32,
// double-buffered LDS (one barrier/iter), XOR-swizzled chunks (0 bank conflicts).
// 1D grid, XCD-aware: the NT n-tiles of one m-slot get linear IDs with equal
// residue mod 8 -> same XCD -> A-slab fetched once into that XCD's L2, reused NT x.
// Requires (Mtot/128 + 8) % 8 == 0.
// FUSE=1: out = bf16 gelu(acc); FUSE=0: out = f32 acc.
template <int FUSE>
__global__ __launch_bounds__(256)
void grouped_gemm(const u16* __restrict__ A, const u16* __restrict__ Bt,
                  void* __restrict__ Out, const int* __restrict__ tokens,
                  int Mtot, int K, int Nn) {
  const int NT = Nn >> 7;
  const int id = blockIdx.x;
  const int xcd = id & 7;
  const int within = id >> 3;
  const int slot = xcd + 8 * (within / NT);  // m-slot
  const int ntile = within % NT;             // n-tile

  int row_start = 0, tiles_before = 0;
  int expert = -1, my_row0 = 0, rows_valid = 0;
#pragma unroll
  for (int e = 0; e < 8; ++e) {
    int t = tokens[e];
    int nt = (t + 127) >> 7;
    if (expert < 0 && slot >= tiles_before && slot < tiles_before + nt) {
      expert = e;
      int mi = slot - tiles_before;
      my_row0 = row_start + mi * 128;
      rows_valid = t - mi * 128;
      if (rows_valid > 128) rows_valid = 128;
    }
    tiles_before += nt;
    row_start += t;
  }
  if (expert < 0) return;  // idle slack slot

  const int n0 = ntile * 128;
  const u16* Bq = Bt + (size_t)expert * Nn * K + (size_t)n0 * K;

  __shared__ __align__(16) u16 lA[2][128 * 32];  // 2 x 8 KB
  __shared__ __align__(16) u16 lB[2][128 * 32];

  const int tid = threadIdx.x;
  const int lane = tid & 63;
  const int wave = tid >> 6;
  const int wm = (wave >> 1) * 64;
  const int wn = (wave & 1) * 64;
  const int fr = lane & 15;
  const int fq = lane >> 4;

  f32x4 acc[4][4];
#pragma unroll
  for (int i = 0; i < 4; ++i)
#pragma unroll
    for (int j = 0; j < 4; ++j) acc[i][j] = (f32x4){0.f, 0.f, 0.f, 0.f};

  // staging: thread tid fills LDS slot (r = h*64 + (tid>>2), c = tid&3), h=0,1,
  // at elem offset h*2048 + tid*8. Source chunk g = c ^ ((r>>1)&3).
  const int sr = tid >> 2;
  const int swz = ((tid & 3) ^ ((sr >> 1) & 3)) * 8;
  int ga0 = my_row0 + sr;       if (ga0 > Mtot - 1) ga0 = Mtot - 1;  // clamp; store-masked
  int ga1 = my_row0 + 64 + sr;  if (ga1 > Mtot - 1) ga1 = Mtot - 1;
  const u16* pA0 = A + (size_t)ga0 * K + swz;
  const u16* pA1 = A + (size_t)ga1 * K + swz;
  const u16* pB0 = Bq + (size_t)sr * K + swz;
  const u16* pB1 = Bq + (size_t)(64 + sr) * K + swz;

  // fragment read: chunk fq of row lives at swizzled column (fq ^ ((fr>>1)&3))
  const int cswz = (fq ^ ((fr >> 1) & 3)) * 8;

  // prefetch tile 0 into buffer 0
  async_ld16(pA0, &lA[0][tid * 8]);
  async_ld16(pA1, &lA[0][2048 + tid * 8]);
  async_ld16(pB0, &lB[0][tid * 8]);
  async_ld16(pB1, &lB[0][2048 + tid * 8]);

  int buf = 0;
  for (int k0 = 0; k0 < K; k0 += 32) {
    __syncthreads();  // vmcnt(0): tile `buf` published; lgkmcnt(0): buf^1 reads done
    if (k0 + 32 < K) {
      const int nb = buf ^ 1;
      async_ld16(pA0 + k0 + 32, &lA[nb][tid * 8]);
      async_ld16(pA1 + k0 + 32, &lA[nb][2048 + tid * 8]);
      async_ld16(pB0 + k0 + 32, &lB[nb][tid * 8]);
      async_ld16(pB1 + k0 + 32, &lB[nb][2048 + tid * 8]);
    }

    bf16x8 aF[4], bF[4];
#pragma unroll
    for (int i = 0; i < 4; ++i)
      aF[i] = *(const bf16x8*)&lA[buf][(wm + i * 16 + fr) * 32 + cswz];
#pragma unroll
    for (int j = 0; j < 4; ++j)
      bF[j] = *(const bf16x8*)&lB[buf][(wn + j * 16 + fr) * 32 + cswz];
#pragma unroll
    for (int i = 0; i < 4; ++i)
#pragma unroll
      for (int j = 0; j < 4; ++j)
        acc[i][j] = __builtin_amdgcn_mfma_f32_16x16x32_bf16(aF[i], bF[j], acc[i][j], 0, 0, 0);
    buf ^= 1;
  }

  // epilogue. C/D layout: col = lane&15, row = (lane>>4)*4 + reg  [m89-verified]
  if (FUSE) {
    u16* Op = (u16*)Out;
#pragma unroll
    for (int i = 0; i < 4; ++i) {
#pragma unroll
      for (int r = 0; r < 4; ++r) {
        int lrow = wm + i * 16 + fq * 4 + r;
        if (lrow < rows_valid) {
          size_t base = (size_t)(my_row0 + lrow) * Nn + (size_t)(n0 + wn + fr);
#pragma unroll
          for (int j = 0; j < 4; ++j)
            Op[base + j * 16] = f32_to_bf16(fast_gelu(acc[i][j][r]));
        }
      }
    }
  } else {
    float* Op = (float*)Out;
#pragma unroll
    for (int i = 0; i < 4; ++i) {
#pragma unroll
      for (int r = 0; r < 4; ++r) {
        int lrow = wm + i * 16 + fq * 4 + r;
        if (lrow < rows_valid) {
          size_t base = (size_t)(my_row0 + lrow) * Nn + (size_t)(n0 + wn + fr);
#pragma unroll
          for (int j = 0; j < 4; ++j) Op[base + j * 16] = acc[i][j][r];
        }
      }
    }
  }
}

extern "C" void kernel_launch(void* const* d_in, const int* in_sizes, int n_in,
                              void* d_out, int out_size, void* d_ws, size_t ws_size,
                              hipStream_t stream) {
  (void)in_sizes; (void)n_in; (void)out_size; (void)ws_size;
  const float* x  = (const float*)d_in[0];   // [N][H]
  const float* w1 = (const float*)d_in[1];   // [E][H][F]
  const float* w2 = (const float*)d_in[2];   // [E][F][H]
  const int* tokens = (const int*)d_in[3];   // [E]

  const int N = 16384, H = 1024, F = 4096, E = 8;

  // ws layout (bf16): x 32MB | w1^T 64MB | w2^T 64MB | intermediate 128MB  (~302 MB)
  u16* x_bf  = (u16*)d_ws;
  u16* w1t   = x_bf + (size_t)N * H;       // [E][F][H]
  u16* w2t   = w1t + (size_t)E * F * H;    // [E][H][F]
  u16* inter = w2t + (size_t)E * H * F;    // [N][F]

  cvt_kernel<<<dim3((N * H / 8 + 255) / 256), dim3(256), 0, stream>>>(x, x_bf, N * H / 8);
  tpose_cvt_kernel<<<dim3(F / 32, H / 32, E), dim3(32, 8), 0, stream>>>(w1, w1t, H, F);
  tpose_cvt_kernel<<<dim3(H / 32, F / 32, E), dim3(32, 8), 0, stream>>>(w2, w2t, F, H);

  const int SLOTS = N / 128 + E;  // 136, divisible by 8 (swizzle requirement)
  // GEMM1: [N][H] x [H][F] -> gelu -> bf16 inter [N][F]
  grouped_gemm<1><<<dim3((F / 128) * SLOTS), dim3(256), 0, stream>>>(
      x_bf, w1t, inter, tokens, N, H, F);
  // GEMM2: [N][F] x [F][H] -> f32 out [N][H]
  grouped_gemm<0><<<dim3((H / 128) * SLOTS), dim3(256), 0, stream>>>(
      inter, w2t, (float*)d_out, tokens, N, F, H);
}